// Round 1
// baseline (1327.641 us; speedup 1.0000x reference)
//
#include <hip/hip_runtime.h>
#include <math.h>

#define NROWS 16384
#define NCOLS 16384
#define DIM   128
#define DIM4  32      // DIM/4
#define TM 128
#define TN 128
#define NSPLIT 2
#define CPS (NCOLS / NSPLIT)   // 8192 cols per split
#define NCH (CPS / TN)         // 64 chunks
#define TOPK 8

// Fused kernel: per block = (row-block rb of 128 rows) x (col split cs of 8192 cols).
// Stages Q tile once, loops C chunks of 128 cols: fp32 register-tiled GEMM,
// writes S to global, overlays tile into LDS, scans for per-row top-8.
__global__ __launch_bounds__(256) void sim_topk_kernel(
    const float* __restrict__ Q, const float* __restrict__ C,
    float* __restrict__ S, float* __restrict__ ws_v, int* __restrict__ ws_i)
{
  __shared__ __align__(16) float a_lds[TM * DIM];  // [k][row ^ (k&28)]
  __shared__ __align__(16) float b_lds[TN * DIM];  // [k][col ^ (k&28)], later scan overlay

  const int t   = threadIdx.x;
  const int bid = blockIdx.x;
  const int rb  = bid >> 1;
  const int cs  = bid & 1;
  const int row0 = rb * TM;
  const int col0 = cs * CPS;

  const int tx  = t & 15;
  const int ty  = (t >> 4) & 15;
  const int tx4 = tx * 4;
  const int ty4 = ty * 4;

  // ---- stage A (Q tile): 128 rows x 128 k, transpose into [k][row], swizzled ----
  {
    const float4* src = (const float4*)Q;
    const int kg = t & 31;
    const int sw = (4 * kg) & 28;
    #pragma unroll
    for (int i = 0; i < 16; ++i) {
      int r = i * 8 + (t >> 5);
      float4 v = src[(size_t)(row0 + r) * DIM4 + kg];
      int k0 = kg * 4;
      int d  = r ^ sw;
      a_lds[(k0 + 0) * TM + d] = v.x;
      a_lds[(k0 + 1) * TM + d] = v.y;
      a_lds[(k0 + 2) * TM + d] = v.z;
      a_lds[(k0 + 3) * TM + d] = v.w;
    }
  }

  // per-thread running top-8 for local row (t>>1), column half (t&1)
  float tv[TOPK];
  int   ti_[TOPK];
  #pragma unroll
  for (int j = 0; j < TOPK; ++j) { tv[j] = -INFINITY; ti_[j] = 0x7fffffff; }
  const int srow = t >> 1;
  const int sh   = t & 1;

  for (int ch = 0; ch < NCH; ++ch) {
    __syncthreads();  // previous scan done reading b_lds; a_lds staged (first iter)

    // ---- stage B (C chunk): 128 cols x 128 k into [k][col], swizzled ----
    {
      const float4* src = (const float4*)C;
      const int crow0 = col0 + ch * TN;
      const int kg = t & 31;
      const int sw = (4 * kg) & 28;
      #pragma unroll
      for (int i = 0; i < 16; ++i) {
        int r = i * 8 + (t >> 5);
        float4 v = src[(size_t)(crow0 + r) * DIM4 + kg];
        int k0 = kg * 4;
        int d  = r ^ sw;
        b_lds[(k0 + 0) * TN + d] = v.x;
        b_lds[(k0 + 1) * TN + d] = v.y;
        b_lds[(k0 + 2) * TN + d] = v.z;
        b_lds[(k0 + 3) * TN + d] = v.w;
      }
    }
    __syncthreads();

    // ---- GEMM: 8x8 micro-tile, rows {ty4..+3, 64+ty4..+3}, cols {tx4..+3, 64+tx4..+3} ----
    float acc[2][4][2][4];
    #pragma unroll
    for (int rg = 0; rg < 2; ++rg)
      #pragma unroll
      for (int i = 0; i < 4; ++i)
        #pragma unroll
        for (int cg = 0; cg < 2; ++cg)
          #pragma unroll
          for (int j = 0; j < 4; ++j)
            acc[rg][i][cg][j] = 0.0f;

    #pragma unroll 4
    for (int k = 0; k < DIM; ++k) {
      const int c = k & 28;
      float4 a0 = *(const float4*)&a_lds[k * TM + (ty4 ^ c)];
      float4 a1 = *(const float4*)&a_lds[k * TM + ((64 + ty4) ^ c)];
      float4 b0 = *(const float4*)&b_lds[k * TN + (tx4 ^ c)];
      float4 b1 = *(const float4*)&b_lds[k * TN + ((64 + tx4) ^ c)];
      float av[2][4] = {{a0.x, a0.y, a0.z, a0.w}, {a1.x, a1.y, a1.z, a1.w}};
      float bv[2][4] = {{b0.x, b0.y, b0.z, b0.w}, {b1.x, b1.y, b1.z, b1.w}};
      #pragma unroll
      for (int rg = 0; rg < 2; ++rg)
        #pragma unroll
        for (int i = 0; i < 4; ++i)
          #pragma unroll
          for (int cg = 0; cg < 2; ++cg)
            #pragma unroll
            for (int j = 0; j < 4; ++j)
              acc[rg][i][cg][j] = fmaf(av[rg][i], bv[cg][j], acc[rg][i][cg][j]);
    }
    __syncthreads();  // everyone done reading b_lds

    // ---- epilogue: write S (global) + scan overlay into b_lds ----
    #pragma unroll
    for (int rg = 0; rg < 2; ++rg) {
      #pragma unroll
      for (int i = 0; i < 4; ++i) {
        const int lrow = rg * 64 + ty4 + i;
        const size_t grow = (size_t)(row0 + lrow);
        const int rs = (lrow & 7) << 2;
        #pragma unroll
        for (int cg = 0; cg < 2; ++cg) {
          const int lcol = cg * 64 + tx4;
          const int gcol = col0 + ch * TN + lcol;
          float4 v = make_float4(acc[rg][i][cg][0], acc[rg][i][cg][1],
                                 acc[rg][i][cg][2], acc[rg][i][cg][3]);
          *(float4*)&S[grow * (size_t)NCOLS + (size_t)gcol] = v;
          *(float4*)&b_lds[lrow * TN + (lcol ^ rs)] = v;
        }
      }
    }
    __syncthreads();  // scan overlay ready

    // ---- scan: 2 threads per row, 64 cols each, ascending col order ----
    {
      const int rs = (srow & 7) << 2;
      const int gbase = col0 + ch * TN + sh * 64;
      #pragma unroll
      for (int cc = 0; cc < 16; ++cc) {
        const int lcol = sh * 64 + cc * 4;
        float4 v = *(const float4*)&b_lds[srow * TN + (lcol ^ rs)];
        float vv[4] = {v.x, v.y, v.z, v.w};
        #pragma unroll
        for (int u = 0; u < 4; ++u) {
          const float val = vv[u];
          if (val > tv[TOPK - 1]) {   // strict >: ties keep earlier (lower) index
            tv[TOPK - 1]  = val;
            ti_[TOPK - 1] = gbase + cc * 4 + u;
            #pragma unroll
            for (int m = TOPK - 1; m > 0; --m) {
              if (tv[m] > tv[m - 1]) {  // strict: equal stays below (older = lower idx)
                float q = tv[m]; tv[m] = tv[m - 1]; tv[m - 1] = q;
                int   w = ti_[m]; ti_[m] = ti_[m - 1]; ti_[m - 1] = w;
              }
            }
          }
        }
      }
    }
  }

  // ---- write partial top-8 lists (4 lists per row: 2 splits x 2 halves) ----
  {
    const int grow = row0 + srow;
    const int li   = cs * 2 + sh;
    const size_t base = ((size_t)grow * 4 + li) * TOPK;
    #pragma unroll
    for (int j = 0; j < TOPK; ++j) { ws_v[base + j] = tv[j]; ws_i[base + j] = ti_[j]; }
  }
}

// Merge 4 partial lists per row -> final top-8; apply >=0 threshold to ids.
__global__ __launch_bounds__(256) void merge_topk(
    const float* __restrict__ ws_v, const int* __restrict__ ws_i,
    float* __restrict__ out)
{
  const int r = blockIdx.x * 256 + threadIdx.x;
  if (r >= NROWS) return;

  float bv[TOPK]; int bi[TOPK];
  #pragma unroll
  for (int j = 0; j < TOPK; ++j) { bv[j] = -INFINITY; bi[j] = 0x7fffffff; }

  #pragma unroll
  for (int li = 0; li < 4; ++li) {
    const size_t base = ((size_t)r * 4 + li) * TOPK;
    #pragma unroll
    for (int j = 0; j < TOPK; ++j) {
      float v = ws_v[base + j];
      int   i = ws_i[base + j];
      bool repl = (v > bv[TOPK - 1]) || (v == bv[TOPK - 1] && i < bi[TOPK - 1]);
      if (repl) {
        bv[TOPK - 1] = v; bi[TOPK - 1] = i;
        #pragma unroll
        for (int m = TOPK - 1; m > 0; --m) {
          bool sw = (bv[m] > bv[m - 1]) || (bv[m] == bv[m - 1] && bi[m] < bi[m - 1]);
          if (sw) {
            float q = bv[m]; bv[m] = bv[m - 1]; bv[m - 1] = q;
            int   w = bi[m]; bi[m] = bi[m - 1]; bi[m - 1] = w;
          }
        }
      }
    }
  }

  float* out_ids  = out;                       // ids as float32
  float* out_sims = out + (size_t)NROWS * TOPK;
  #pragma unroll
  for (int j = 0; j < TOPK; ++j) {
    out_sims[(size_t)r * TOPK + j] = bv[j];
    out_ids [(size_t)r * TOPK + j] = (bv[j] >= 0.0f) ? (float)bi[j] : -1.0f;
  }
}

extern "C" void kernel_launch(void* const* d_in, const int* in_sizes, int n_in,
                              void* d_out, int out_size, void* d_ws, size_t ws_size,
                              hipStream_t stream) {
  const float* Q = (const float*)d_in[0];
  const float* C = (const float*)d_in[1];
  float* out = (float*)d_out;
  float* S   = out + (size_t)2 * NROWS * TOPK;           // all_similarities region
  float* ws_v = (float*)d_ws;                            // 16384*4*8 floats = 2 MB
  int*   ws_i = (int*)((float*)d_ws + (size_t)NROWS * 4 * TOPK);  // +2 MB

  sim_topk_kernel<<<dim3((NROWS / TM) * NSPLIT), dim3(256), 0, stream>>>(Q, C, S, ws_v, ws_i);
  merge_topk<<<dim3(NROWS / 256), dim3(256), 0, stream>>>(ws_v, ws_i, out);
}

// Round 2
// 1189.262 us; speedup vs baseline: 1.1164x; 1.1164x over previous
//
#include <hip/hip_runtime.h>
#include <math.h>

#define NROWS 16384
#define NCOLS 16384
#define DIM   128
#define TM    128
#define TN    64
#define NSPLIT 2
#define CPS   (NCOLS/NSPLIT)      // 8192 cols per split
#define NCH   (CPS/TN)            // 128 chunks
#define KP    12                  // candidates per partial list

typedef __attribute__((ext_vector_type(8))) short bf16x8;
typedef __attribute__((ext_vector_type(4))) float f32x4;

// LDS byte map (131072 B total):
//   A_hi [0,32768): 32 tiles (rowblk*4+kb), 1 KB each (64 lanes x 16 B fragment slots)
//   A_lo [32768,65536)
//   B[p] at 65536 + p*32768: hi [0,16384), lo [16384,32768); 16 tiles (colblk*4+kb)
//   Overlay (epilogue): fp32 [128][64] swizzled, reuses B[cur]'s 32 KB
#define AHI   0u
#define ALO   32768u
#define BBASE 65536u

__device__ __forceinline__ unsigned short bf16_rne(float x) {
  unsigned u = __float_as_uint(x);
  unsigned r = u + 0x7fffu + ((u >> 16) & 1u);
  return (unsigned short)(r >> 16);
}

__global__ __launch_bounds__(256, 1) void sim_topk_kernel(
    const float* __restrict__ Q, const float* __restrict__ C,
    float* __restrict__ S, int* __restrict__ ws_i)
{
  __shared__ __align__(16) unsigned char lds[131072];
  const int t   = threadIdx.x;
  const int bid = blockIdx.x;
  const int rb  = bid >> 1;
  const int cs  = bid & 1;
  const int row0  = rb * TM;
  const int ccol0 = cs * CPS;
  const int w    = t >> 6;
  const int lane = t & 63;

  const f32x4* Q4 = (const f32x4*)Q;
  const f32x4* C4 = (const f32x4*)C;

  // ---- stage A tile (once): fp32 -> bf16 hi/lo, tiled-fragment layout ----
  #pragma unroll
  for (int j = 0; j < 2; ++j) {
    int u    = t * 2 + j;       // 0..511
    int arow = u >> 2;          // 0..127
    int kg   = u & 3;           // k-group of 32
    f32x4 g[8];
    #pragma unroll
    for (int i = 0; i < 8; ++i)
      g[i] = Q4[(size_t)(row0 + arow) * 32 + kg * 8 + i];
    int at = (arow >> 4) * 4 + kg;
    unsigned tb = AHI + ((unsigned)at << 10);
    unsigned sw = ((unsigned)(at & 7)) << 4;
    #pragma unroll
    for (int s = 0; s < 4; ++s) {
      bf16x8 h, l;
      #pragma unroll
      for (int e = 0; e < 8; ++e) {
        float x = g[s * 2 + (e >> 2)][e & 3];
        unsigned short hb = bf16_rne(x);
        float xh = __uint_as_float((unsigned)hb << 16);
        unsigned short lb = bf16_rne(x - xh);
        h[e] = (short)hb; l[e] = (short)lb;
      }
      unsigned ln   = (unsigned)((arow & 15) | (s << 4));
      unsigned addr = tb + ((ln << 4) ^ sw);
      *(bf16x8*)&lds[addr]          = h;
      *(bf16x8*)&lds[addr + 32768u] = l;
    }
  }

  // ---- B staging machinery (reg-staged async: issue early, write late) ----
  f32x4 f[8];
  const int scol = t >> 2;  // 0..63 (col within chunk)
  const int skg  = t & 3;   // k-group
  auto issueB = [&](int ch) {
    const size_t srcrow = (size_t)(ccol0 + ch * TN + scol);
    #pragma unroll
    for (int i = 0; i < 8; ++i)
      f[i] = C4[srcrow * 32 + skg * 8 + i];
  };
  auto writeB = [&](unsigned bbuf) {
    int bt = (scol >> 4) * 4 + skg;
    unsigned tb = bbuf + ((unsigned)bt << 10);
    unsigned sw = ((unsigned)(bt & 7)) << 4;
    #pragma unroll
    for (int s = 0; s < 4; ++s) {
      bf16x8 h, l;
      #pragma unroll
      for (int e = 0; e < 8; ++e) {
        float x = f[s * 2 + (e >> 2)][e & 3];
        unsigned short hb = bf16_rne(x);
        float xh = __uint_as_float((unsigned)hb << 16);
        unsigned short lb = bf16_rne(x - xh);
        h[e] = (short)hb; l[e] = (short)lb;
      }
      unsigned ln   = (unsigned)((scol & 15) | (s << 4));
      unsigned addr = tb + ((ln << 4) ^ sw);
      *(bf16x8*)&lds[addr]          = h;
      *(bf16x8*)&lds[addr + 16384u] = l;
    }
  };

  issueB(0); writeB(BBASE); issueB(1);
  __syncthreads();

  // per-thread top-KP candidates: row (t>>1), column half (t&1)
  float tv[KP]; int ti[KP];
  #pragma unroll
  for (int j = 0; j < KP; ++j) { tv[j] = -INFINITY; ti[j] = 0x7fffffff; }
  const int srow = t >> 1;
  const int sh   = t & 1;

  const int wr = (w >> 1) * 4;  // wave's A rowblk base (x16 rows)
  const int wc = (w & 1) * 2;   // wave's B colblk base (x16 cols)

  for (int ch = 0; ch < NCH; ++ch) {
    const unsigned bb = BBASE + ((unsigned)(ch & 1) << 15);
    const unsigned bo = BBASE + ((unsigned)((ch & 1) ^ 1) << 15);

    f32x4 acc[4][2];
    #pragma unroll
    for (int a = 0; a < 4; ++a)
      #pragma unroll
      for (int b = 0; b < 2; ++b)
        acc[a][b] = 0.0f;

    // ---- MFMA: 3-term bf16x2 GEMM, wave tile 64x32 ----
    #pragma unroll
    for (int ks = 0; ks < 4; ++ks) {
      bf16x8 ah[4], al[4], bh[2], bl[2];
      #pragma unroll
      for (int rbk = 0; rbk < 4; ++rbk) {
        int at = (wr + rbk) * 4 + ks;
        unsigned off = ((unsigned)at << 10) +
                       ((((unsigned)lane) << 4) ^ (((unsigned)(at & 7)) << 4));
        ah[rbk] = *(const bf16x8*)&lds[AHI + off];
        al[rbk] = *(const bf16x8*)&lds[ALO + off];
      }
      #pragma unroll
      for (int cbk = 0; cbk < 2; ++cbk) {
        int bt = (wc + cbk) * 4 + ks;
        unsigned off = ((unsigned)bt << 10) +
                       ((((unsigned)lane) << 4) ^ (((unsigned)(bt & 7)) << 4));
        bh[cbk] = *(const bf16x8*)&lds[bb + off];
        bl[cbk] = *(const bf16x8*)&lds[bb + 16384u + off];
      }
      #pragma unroll
      for (int rbk = 0; rbk < 4; ++rbk)
        #pragma unroll
        for (int cbk = 0; cbk < 2; ++cbk) {
          acc[rbk][cbk] = __builtin_amdgcn_mfma_f32_16x16x32_bf16(ah[rbk], bh[cbk], acc[rbk][cbk], 0, 0, 0);
          acc[rbk][cbk] = __builtin_amdgcn_mfma_f32_16x16x32_bf16(ah[rbk], bl[cbk], acc[rbk][cbk], 0, 0, 0);
          acc[rbk][cbk] = __builtin_amdgcn_mfma_f32_16x16x32_bf16(al[rbk], bh[cbk], acc[rbk][cbk], 0, 0, 0);
        }
    }

    // stage chunk ch+1 into the other B buffer; prefetch ch+2
    if (ch + 1 < NCH) {
      writeB(bo);
      issueB(ch + 2 < NCH ? ch + 2 : ch);
    }
    __syncthreads();  // all ds_reads of bb done; bo staged

    // ---- transpose acc -> fp32 overlay (swizzled) reusing bb ----
    #pragma unroll
    for (int rbk = 0; rbk < 4; ++rbk)
      #pragma unroll
      for (int cbk = 0; cbk < 2; ++cbk)
        #pragma unroll
        for (int e = 0; e < 4; ++e) {
          int orow = (wr + rbk) * 16 + (lane >> 4) * 4 + e;
          int ocol = (wc + cbk) * 16 + (lane & 15);
          unsigned off = (unsigned)orow * 256u +
                         ((((unsigned)ocol) << 2) ^ (((unsigned)(orow & 15)) << 4));
          *(float*)&lds[bb + off] = acc[rbk][cbk][e];
        }
    __syncthreads();

    // ---- scan + coalesced S store ----
    {
      unsigned rsw = ((unsigned)(srow & 15)) << 4;
      const size_t srowg = (size_t)(row0 + srow) * NCOLS;
      const int colg0 = ccol0 + ch * TN;
      #pragma unroll
      for (int cc = 0; cc < 8; ++cc) {
        int colb = sh * 32 + cc * 4;
        unsigned off = (unsigned)srow * 256u + ((((unsigned)colb) << 2) ^ rsw);
        f32x4 v = *(const f32x4*)&lds[bb + off];
        *(f32x4*)&S[srowg + (size_t)(colg0 + colb)] = v;
        #pragma unroll
        for (int u2 = 0; u2 < 4; ++u2) {
          float val = v[u2];
          if (val > tv[KP - 1]) {
            tv[KP - 1] = val; ti[KP - 1] = colg0 + colb + u2;
            #pragma unroll
            for (int m = KP - 1; m > 0; --m) {
              if (tv[m] > tv[m - 1]) {
                float q = tv[m]; tv[m] = tv[m - 1]; tv[m - 1] = q;
                int x2 = ti[m]; ti[m] = ti[m - 1]; ti[m - 1] = x2;
              }
            }
          }
        }
      }
    }
    __syncthreads();  // scan of bb done before next chunk re-stages it
  }

  // ---- write candidate index lists: [row][4 lists][KP] ----
  {
    const int li = cs * 2 + sh;
    const size_t base = ((size_t)(row0 + srow) * 4 + li) * KP;
    #pragma unroll
    for (int j = 0; j < KP; ++j) ws_i[base + j] = ti[j];
  }
}

// Exact re-rank: one wave per row, fp64 dots over 48 candidates -> top-8.
__global__ __launch_bounds__(256) void rerank_kernel(
    const float* __restrict__ Q, const float* __restrict__ C,
    const int* __restrict__ ws_i, float* __restrict__ out)
{
  const int t = threadIdx.x, w = t >> 6, lane = t & 63;
  const int r = blockIdx.x * 4 + w;
  const f32x4* Q4 = (const f32x4*)Q;
  const f32x4* C4 = (const f32x4*)C;

  int cidx = 0;
  if (lane < 48) cidx = ws_i[(size_t)r * 48 + lane];

  double acc = 0.0;
  #pragma unroll 8
  for (int d4 = 0; d4 < 32; ++d4) {
    f32x4 q = Q4[(size_t)r * 32 + d4];
    f32x4 c = C4[(size_t)cidx * 32 + d4];
    acc += (double)q[0] * (double)c[0];
    acc += (double)q[1] * (double)c[1];
    acc += (double)q[2] * (double)c[2];
    acc += (double)q[3] * (double)c[3];
  }

  double mv = (lane < 48) ? acc : -1.0e300;
  int    mi = (lane < 48) ? cidx : 0x7fffffff;

  float* oi = out;                           // ids as float32
  float* os = out + (size_t)NROWS * 8;       // top-8 sims

  for (int k = 0; k < 8; ++k) {
    double bv = mv; int bi = mi;
    #pragma unroll
    for (int off = 32; off >= 1; off >>= 1) {
      double ov = __shfl_xor(bv, off);
      int    o2 = __shfl_xor(bi, off);
      if (ov > bv || (ov == bv && o2 < bi)) { bv = ov; bi = o2; }
    }
    if (lane == 0) {
      os[(size_t)r * 8 + k] = (float)bv;
      oi[(size_t)r * 8 + k] = (bv >= 0.0) ? (float)bi : -1.0f;
    }
    if (mi == bi) mv = -1.0e300;  // candidate indices are unique per row
  }
}

extern "C" void kernel_launch(void* const* d_in, const int* in_sizes, int n_in,
                              void* d_out, int out_size, void* d_ws, size_t ws_size,
                              hipStream_t stream) {
  const float* Q = (const float*)d_in[0];
  const float* C = (const float*)d_in[1];
  float* out = (float*)d_out;
  float* S   = out + (size_t)2 * NROWS * 8;   // all_similarities region
  int* ws_i  = (int*)d_ws;                    // 16384*48*4 B = 3 MB

  sim_topk_kernel<<<dim3((NROWS / TM) * NSPLIT), dim3(256), 0, stream>>>(Q, C, S, ws_i);
  rerank_kernel<<<dim3(NROWS / 4), dim3(256), 0, stream>>>(Q, C, ws_i, out);
}

// Round 3
// 669.882 us; speedup vs baseline: 1.9819x; 1.7753x over previous
//
#include <hip/hip_runtime.h>
#include <math.h>

#define NROWS 16384
#define NCOLS 16384
#define DIM   128
#define TM    128
#define TN    32
#define NSPLIT 4
#define CPS   (NCOLS/NSPLIT)   // 4096 cols per split
#define NCH   (CPS/TN)         // 128 chunks
#define KP    8

typedef __attribute__((ext_vector_type(8))) short bf16x8;
typedef __attribute__((ext_vector_type(4))) float f32x4;

__device__ __forceinline__ unsigned short bf16_rne(float x) {
  unsigned u = __float_as_uint(x);
  unsigned r = u + 0x7fffu + ((u >> 16) & 1u);
  return (unsigned short)(r >> 16);
}

// ---- kernel 0: split C (fp32) -> Chi/Clo (bf16), row-major [16384][128] ----
__global__ __launch_bounds__(256) void split_kernel(
    const float* __restrict__ C,
    unsigned short* __restrict__ Chi, unsigned short* __restrict__ Clo)
{
  const f32x4* C4 = (const f32x4*)C;
  size_t i0 = (size_t)blockIdx.x * 256 + threadIdx.x;
  #pragma unroll
  for (int r = 0; r < 2; ++r) {
    size_t idx = i0 + (size_t)r * 262144;   // total 524288 f32x4
    f32x4 v = C4[idx];
    unsigned short h[4], l[4];
    #pragma unroll
    for (int e = 0; e < 4; ++e) {
      h[e] = bf16_rne(v[e]);
      float xh = __uint_as_float((unsigned)h[e] << 16);
      l[e] = bf16_rne(v[e] - xh);
    }
    unsigned long long hp = (unsigned long long)h[0] | ((unsigned long long)h[1] << 16) |
                            ((unsigned long long)h[2] << 32) | ((unsigned long long)h[3] << 48);
    unsigned long long lp = (unsigned long long)l[0] | ((unsigned long long)l[1] << 16) |
                            ((unsigned long long)l[2] << 32) | ((unsigned long long)l[3] << 48);
    *(unsigned long long*)&Chi[idx * 4] = hp;
    *(unsigned long long*)&Clo[idx * 4] = lp;
  }
}

// ---- kernel 1: fused GEMM (bf16x2, 4-term) + S store + per-split top-8 candidates ----
// 512 threads (8 waves), TM=128 rows/block, NSPLIT=4 col-splits, TN=32-col chunks.
// LDS 32KB: two 16KB B buffers (hi at +0, lo at +8192 within each); overlay reuses dead buf.
__global__ __launch_bounds__(512, 4) void sim_topk_kernel(
    const float* __restrict__ Q,
    const unsigned short* __restrict__ Chi, const unsigned short* __restrict__ Clo,
    float* __restrict__ S, int* __restrict__ cand)
{
  __shared__ __align__(16) unsigned char lds[32768];
  const int t = threadIdx.x;
  const int w = t >> 6, lane = t & 63;

  // XCD-aware mapping: xcd = bid&7; split = xcd>>1 (2 XCDs per split, L2 holds 2MB split)
  const int bid = blockIdx.x;
  const int xcd = bid & 7;
  const int cs  = xcd >> 1;                       // 0..3
  const int rb  = ((xcd & 1) << 6) | (bid >> 3);  // 0..127
  const int row0 = rb * TM;
  const int col0 = cs * CPS;

  // ---- A fragments in registers: wave w owns rows [row0+16w, +16), hi/lo bf16 ----
  bf16x8 ah[4], al[4];
  {
    const int grow = row0 + w * 16 + (lane & 15);
    const f32x4* Q4 = (const f32x4*)(Q + (size_t)grow * DIM);
    #pragma unroll
    for (int ks = 0; ks < 4; ++ks) {
      f32x4 x0 = Q4[ks * 8 + (lane >> 4) * 2];
      f32x4 x1 = Q4[ks * 8 + (lane >> 4) * 2 + 1];
      #pragma unroll
      for (int e = 0; e < 8; ++e) {
        float x = (e < 4) ? x0[e & 3] : x1[e & 3];
        unsigned short hb = bf16_rne(x);
        float xh = __uint_as_float((unsigned)hb << 16);
        unsigned short lb = bf16_rne(x - xh);
        ah[ks][e] = (short)hb;
        al[ks][e] = (short)lb;
      }
    }
  }

  // ---- B staging: thread t stages fragment slot (tile T = t>>6, slot-lane t&63) ----
  // LDS tile layout (per 16KB buf): hi tile (cbk*4+ks) at T*1024 + lane*16; lo at +8192.
  const int sT  = t >> 6;       // 0..7 -> (cbk = sT>>2, ks = sT&3)
  const int sl  = t & 63;
  bf16x8 rh, rl;
  auto gload = [&](int ch) {
    size_t off = (size_t)(col0 + ch * TN + ((sT >> 2) << 4) + (sl & 15)) * DIM
               + (size_t)((sT & 3) * 32 + ((sl >> 4) << 3));
    rh = *(const bf16x8*)&Chi[off];
    rl = *(const bf16x8*)&Clo[off];
  };
  auto swrite = [&](unsigned buf) {
    unsigned off = buf + ((unsigned)sT << 10) + ((unsigned)sl << 4);
    *(bf16x8*)&lds[off]          = rh;
    *(bf16x8*)&lds[off + 8192u]  = rl;
  };

  gload(0); swrite(0u); gload(1);
  __syncthreads();   // buf0 staged

  // per-thread top-KP: row = t>>2, col segment = t&3
  float tv[KP]; int ti[KP];
  #pragma unroll
  for (int j = 0; j < KP; ++j) { tv[j] = -INFINITY; ti[j] = 0x7fffffff; }
  const int srow = t >> 2;
  const int sseg = t & 3;

  for (int ch = 0; ch < NCH; ++ch) {
    const unsigned cur = (ch & 1) ? 16384u : 0u;
    const unsigned nxt = cur ^ 16384u;

    // stage next chunk (regs from last gload), then prefetch chunk+2
    if (ch + 1 < NCH) {
      swrite(nxt);
      if (ch + 2 < NCH) gload(ch + 2);
    }

    // ---- MFMA: 4-term bf16x2, wave tile 16 rows x 32 cols ----
    f32x4 acc0 = {0.f, 0.f, 0.f, 0.f};
    f32x4 acc1 = {0.f, 0.f, 0.f, 0.f};
    #pragma unroll
    for (int ks = 0; ks < 4; ++ks) {
      unsigned o0 = cur + ((unsigned)(0 * 4 + ks) << 10) + ((unsigned)lane << 4);
      unsigned o1 = cur + ((unsigned)(1 * 4 + ks) << 10) + ((unsigned)lane << 4);
      bf16x8 bh0 = *(const bf16x8*)&lds[o0];
      bf16x8 bl0 = *(const bf16x8*)&lds[o0 + 8192u];
      bf16x8 bh1 = *(const bf16x8*)&lds[o1];
      bf16x8 bl1 = *(const bf16x8*)&lds[o1 + 8192u];
      acc0 = __builtin_amdgcn_mfma_f32_16x16x32_bf16(ah[ks], bh0, acc0, 0, 0, 0);
      acc0 = __builtin_amdgcn_mfma_f32_16x16x32_bf16(ah[ks], bl0, acc0, 0, 0, 0);
      acc0 = __builtin_amdgcn_mfma_f32_16x16x32_bf16(al[ks], bh0, acc0, 0, 0, 0);
      acc0 = __builtin_amdgcn_mfma_f32_16x16x32_bf16(al[ks], bl0, acc0, 0, 0, 0);
      acc1 = __builtin_amdgcn_mfma_f32_16x16x32_bf16(ah[ks], bh1, acc1, 0, 0, 0);
      acc1 = __builtin_amdgcn_mfma_f32_16x16x32_bf16(ah[ks], bl1, acc1, 0, 0, 0);
      acc1 = __builtin_amdgcn_mfma_f32_16x16x32_bf16(al[ks], bh1, acc1, 0, 0, 0);
      acc1 = __builtin_amdgcn_mfma_f32_16x16x32_bf16(al[ks], bl1, acc1, 0, 0, 0);
    }
    __syncthreads();   // all frag reads of cur done; nxt fully staged

    // ---- overlay acc -> cur as fp32 [128][32], row-XOR swizzled ----
    #pragma unroll
    for (int e = 0; e < 4; ++e) {
      int orow = w * 16 + (lane >> 4) * 4 + e;
      unsigned rs = ((unsigned)orow & 7u) << 4;
      unsigned ob = cur + (unsigned)orow * 128u;
      int oc0 = (lane & 15);
      int oc1 = 16 + (lane & 15);
      *(float*)&lds[ob + (((unsigned)oc0 << 2) ^ rs)] = acc0[e];
      *(float*)&lds[ob + (((unsigned)oc1 << 2) ^ rs)] = acc1[e];
    }
    __syncthreads();

    // ---- scan + dense S store: 4 threads/row; v0 = cols [seg*4], v1 = cols [16+seg*4] ----
    {
      unsigned rs = ((unsigned)srow & 7u) << 4;
      unsigned ob = cur + (unsigned)srow * 128u;
      f32x4 v0 = *(const f32x4*)&lds[ob + ((((unsigned)sseg) << 4) ^ rs)];
      f32x4 v1 = *(const f32x4*)&lds[ob + ((64u + (((unsigned)sseg) << 4)) ^ rs)];
      const int colg0 = col0 + ch * TN;
      float* srow_p = &S[(size_t)(row0 + srow) * NCOLS + colg0];
      *(f32x4*)&srow_p[sseg * 4]      = v0;
      *(f32x4*)&srow_p[16 + sseg * 4] = v1;
      #pragma unroll
      for (int u = 0; u < 8; ++u) {
        float val = (u < 4) ? v0[u & 3] : v1[u & 3];
        int   gi  = colg0 + ((u < 4) ? (sseg * 4 + u) : (16 + sseg * 4 + (u & 3)));
        if (val > tv[KP - 1]) {
          tv[KP - 1] = val; ti[KP - 1] = gi;
          #pragma unroll
          for (int m = KP - 1; m > 0; --m) {
            if (tv[m] > tv[m - 1]) {
              float q = tv[m]; tv[m] = tv[m - 1]; tv[m - 1] = q;
              int   x = ti[m]; ti[m] = ti[m - 1]; ti[m - 1] = x;
            }
          }
        }
      }
    }
    __syncthreads();   // scan reads done -> next iter may re-stage cur
  }

  // ---- merge 4 segment-lists per row -> per-split top-8 candidate ids ----
  {
    unsigned base = (unsigned)srow * 256u + (unsigned)sseg * 64u;
    #pragma unroll
    for (int j = 0; j < KP; ++j) {
      *(float*)&lds[base + j * 8]     = tv[j];
      *(int*)  &lds[base + j * 8 + 4] = ti[j];
    }
  }
  __syncthreads();
  if (sseg == 0) {
    unsigned rbase = (unsigned)srow * 256u;
    int* dst = cand + ((size_t)(row0 + srow) * NSPLIT + cs) * KP;
    #pragma unroll
    for (int j = 0; j < KP; ++j) {
      float bestv = -INFINITY; int besti = 0x7fffffff; unsigned bo = rbase;
      for (int q = 0; q < 32; ++q) {
        float v = *(float*)&lds[rbase + q * 8];
        int   i = *(int*)  &lds[rbase + q * 8 + 4];
        if (v > bestv || (v == bestv && i < besti)) { bestv = v; besti = i; bo = rbase + q * 8; }
      }
      *(float*)&lds[bo] = -INFINITY;
      dst[j] = besti;
    }
  }
}

// ---- kernel 2: exact fp64 re-rank of 32 candidates/row -> ids + top-8 sims ----
__global__ __launch_bounds__(256) void rerank_kernel(
    const float* __restrict__ Q, const float* __restrict__ C,
    const int* __restrict__ cand, float* __restrict__ out)
{
  const int t = threadIdx.x, w = t >> 6, lane = t & 63;
  const int r = blockIdx.x * 4 + w;
  const f32x4* Q4 = (const f32x4*)(Q + (size_t)r * DIM);

  int cidx = 0;
  if (lane < 32) cidx = cand[(size_t)r * 32 + lane];
  const f32x4* C4 = (const f32x4*)(C + (size_t)cidx * DIM);

  double acc = 0.0;
  #pragma unroll 8
  for (int d4 = 0; d4 < 32; ++d4) {
    f32x4 q = Q4[d4];
    f32x4 c = C4[d4];
    acc += (double)q[0] * (double)c[0];
    acc += (double)q[1] * (double)c[1];
    acc += (double)q[2] * (double)c[2];
    acc += (double)q[3] * (double)c[3];
  }

  double mv = (lane < 32) ? acc : -1.0e300;
  int    mi = (lane < 32) ? cidx : 0x7fffffff;

  float* oi = out;                           // ids as float32
  float* os = out + (size_t)NROWS * 8;       // top-8 sims

  for (int k = 0; k < 8; ++k) {
    double bv = mv; int bi = mi;
    #pragma unroll
    for (int off = 32; off >= 1; off >>= 1) {
      double ov = __shfl_xor(bv, off);
      int    o2 = __shfl_xor(bi, off);
      if (ov > bv || (ov == bv && o2 < bi)) { bv = ov; bi = o2; }
    }
    if (lane == 0) {
      os[(size_t)r * 8 + k] = (float)bv;
      oi[(size_t)r * 8 + k] = (bv >= 0.0) ? (float)bi : -1.0f;
    }
    if (mi == bi) mv = -1.0e300;   // candidate ids unique per row
  }
}

extern "C" void kernel_launch(void* const* d_in, const int* in_sizes, int n_in,
                              void* d_out, int out_size, void* d_ws, size_t ws_size,
                              hipStream_t stream) {
  const float* Q = (const float*)d_in[0];
  const float* C = (const float*)d_in[1];
  float* out = (float*)d_out;
  float* S   = out + (size_t)2 * NROWS * 8;              // all_similarities

  unsigned short* Chi = (unsigned short*)d_ws;           // 4MB
  unsigned short* Clo = Chi + (size_t)NCOLS * DIM;       // 4MB
  int* cand = (int*)(Clo + (size_t)NCOLS * DIM);         // 2MB: [16384][4][8]

  split_kernel<<<dim3(1024), dim3(256), 0, stream>>>(C, Chi, Clo);
  sim_topk_kernel<<<dim3((NROWS / TM) * NSPLIT), dim3(512), 0, stream>>>(Q, Chi, Clo, S, cand);
  rerank_kernel<<<dim3(NROWS / 4), dim3(256), 0, stream>>>(Q, C, cand, out);
}

// Round 4
// 586.643 us; speedup vs baseline: 2.2631x; 1.1419x over previous
//
#include <hip/hip_runtime.h>
#include <math.h>

#define NROWS 16384
#define NCOLS 16384
#define DIM   128
#define TM    128
#define TN    64
#define NSPLIT 4
#define CPS   (NCOLS/NSPLIT)   // 4096 cols per split
#define NCH   (CPS/TN)         // 64 chunks
#define KP    8

typedef __attribute__((ext_vector_type(8))) short bf16x8;
typedef __attribute__((ext_vector_type(4))) float f32x4;

__device__ __forceinline__ unsigned short bf16_rne(float x) {
  unsigned u = __float_as_uint(x);
  unsigned r = u + 0x7fffu + ((u >> 16) & 1u);
  return (unsigned short)(r >> 16);
}

// ---- kernel 0: split C (fp32) -> Chi/Clo (bf16), row-major [16384][128] ----
__global__ __launch_bounds__(256) void split_kernel(
    const float* __restrict__ C,
    unsigned short* __restrict__ Chi, unsigned short* __restrict__ Clo)
{
  const f32x4* C4 = (const f32x4*)C;
  size_t i0 = (size_t)blockIdx.x * 256 + threadIdx.x;
  #pragma unroll
  for (int r = 0; r < 2; ++r) {
    size_t idx = i0 + (size_t)r * 262144;   // total 524288 f32x4
    f32x4 v = C4[idx];
    unsigned short h[4], l[4];
    #pragma unroll
    for (int e = 0; e < 4; ++e) {
      h[e] = bf16_rne(v[e]);
      float xh = __uint_as_float((unsigned)h[e] << 16);
      l[e] = bf16_rne(v[e] - xh);
    }
    unsigned long long hp = (unsigned long long)h[0] | ((unsigned long long)h[1] << 16) |
                            ((unsigned long long)h[2] << 32) | ((unsigned long long)h[3] << 48);
    unsigned long long lp = (unsigned long long)l[0] | ((unsigned long long)l[1] << 16) |
                            ((unsigned long long)l[2] << 32) | ((unsigned long long)l[3] << 48);
    *(unsigned long long*)&Chi[idx * 4] = hp;
    *(unsigned long long*)&Clo[idx * 4] = lp;
  }
}

// ---- kernel 1: fused GEMM (swapped-operand MFMA, 3-term bf16x2) + direct S store
//      + per-thread per-row top-8 candidates. 512 threads, TM=128, TN=64.
// LDS 64KB: two 32KB B buffers; within buffer hi [0,16K), lo [16K,32K).
// Tile T (=cbk*4+ks) at T*1024 + lane*16: lane -> col=(T>>2)*16+(lane&15),
// k=(T&3)*32+(lane>>4)*8.
__global__ __launch_bounds__(512, 4) void sim_topk_kernel(
    const float* __restrict__ Q,
    const unsigned short* __restrict__ Chi, const unsigned short* __restrict__ Clo,
    float* __restrict__ S, int* __restrict__ cand)
{
  __shared__ __align__(16) unsigned char lds[65536];
  const int t = threadIdx.x;
  const int w = t >> 6, lane = t & 63;

  // XCD-aware mapping: 2 XCDs per col-split; split's Chi+Clo (4MB) fits XCD L2
  const int bid = blockIdx.x;
  const int xcd = bid & 7;
  const int cs  = xcd >> 1;                       // 0..3
  const int rb  = ((xcd & 1) << 6) | (bid >> 3);  // 0..127
  const int row0 = rb * TM;
  const int col0 = cs * CPS;

  // ---- A fragments in registers (used as SECOND mfma operand) ----
  // wave w owns rows [row0+16w, +16); lane's S-row = arow
  bf16x8 ah[4], al[4];
  const int arow = row0 + w * 16 + (lane & 15);
  {
    const f32x4* Q4 = (const f32x4*)(Q + (size_t)arow * DIM);
    #pragma unroll
    for (int ks = 0; ks < 4; ++ks) {
      f32x4 x0 = Q4[ks * 8 + (lane >> 4) * 2];
      f32x4 x1 = Q4[ks * 8 + (lane >> 4) * 2 + 1];
      #pragma unroll
      for (int e = 0; e < 8; ++e) {
        float x = (e < 4) ? x0[e & 3] : x1[e & 3];
        unsigned short hb = bf16_rne(x);
        float xh = __uint_as_float((unsigned)hb << 16);
        unsigned short lb = bf16_rne(x - xh);
        ah[ks][e] = (short)hb;
        al[ks][e] = (short)lb;
      }
    }
  }

  // ---- B staging: thread t -> tile T=t>>5, lanes ln0=(t&31)*2, ln0+1 ----
  const int sT  = t >> 5;              // 0..15
  const int ln0 = (t & 31) * 2;        // even lane in tile
  const int scol = (sT >> 2) * 16 + (ln0 & 15);
  const int sk   = (sT & 3) * 32 + (ln0 >> 4) * 8;
  bf16x8 rh0, rh1, rl0, rl1;
  auto gload = [&](int ch) {
    size_t base = (size_t)(col0 + ch * TN + scol) * DIM + sk;
    rh0 = *(const bf16x8*)&Chi[base];
    rh1 = *(const bf16x8*)&Chi[base + DIM];
    rl0 = *(const bf16x8*)&Clo[base];
    rl1 = *(const bf16x8*)&Clo[base + DIM];
  };
  auto swrite = [&](unsigned buf) {
    unsigned off = buf + ((unsigned)sT << 10) + ((unsigned)ln0 << 4);
    *(bf16x8*)&lds[off]           = rh0;
    *(bf16x8*)&lds[off + 16]      = rh1;
    *(bf16x8*)&lds[off + 16384u]      = rl0;
    *(bf16x8*)&lds[off + 16384u + 16] = rl1;
  };

  gload(0); swrite(0u); gload(1);
  __syncthreads();   // buf0 staged

  float tv[KP]; int ti[KP];
  #pragma unroll
  for (int j = 0; j < KP; ++j) { tv[j] = -INFINITY; ti[j] = 0x7fffffff; }

  for (int ch = 0; ch < NCH; ++ch) {
    const unsigned cur = (ch & 1) ? 32768u : 0u;
    const unsigned nxt = cur ^ 32768u;

    // stage next chunk (regs from previous gload), prefetch chunk+2
    if (ch + 1 < NCH) swrite(nxt);
    if (ch + 2 < NCH) gload(ch + 2);

    // ---- MFMA: 3-term (hh, hl, lh), swapped operands; wave tile 16 rows x 64 cols ----
    f32x4 acc[4];
    #pragma unroll
    for (int c = 0; c < 4; ++c) acc[c] = {0.f, 0.f, 0.f, 0.f};
    #pragma unroll
    for (int ks = 0; ks < 4; ++ks) {
      #pragma unroll
      for (int cbk = 0; cbk < 4; ++cbk) {
        unsigned o = cur + ((unsigned)(cbk * 4 + ks) << 10) + ((unsigned)lane << 4);
        bf16x8 bh = *(const bf16x8*)&lds[o];
        bf16x8 bl = *(const bf16x8*)&lds[o + 16384u];
        acc[cbk] = __builtin_amdgcn_mfma_f32_16x16x32_bf16(bh, ah[ks], acc[cbk], 0, 0, 0);
        acc[cbk] = __builtin_amdgcn_mfma_f32_16x16x32_bf16(bl, ah[ks], acc[cbk], 0, 0, 0);
        acc[cbk] = __builtin_amdgcn_mfma_f32_16x16x32_bf16(bh, al[ks], acc[cbk], 0, 0, 0);
      }
    }

    // ---- epilogue: direct f32x4 S stores + per-thread top-k on own row ----
    {
      const int colg0 = col0 + ch * TN;
      const int cloc  = (lane >> 4) * 4;            // 4-col group within 16
      float* sp = &S[(size_t)arow * NCOLS + colg0 + cloc];
      #pragma unroll
      for (int cbk = 0; cbk < 4; ++cbk) {
        *(f32x4*)&sp[cbk * 16] = acc[cbk];
        #pragma unroll
        for (int e = 0; e < 4; ++e) {
          float val = acc[cbk][e];
          if (val > tv[KP - 1]) {
            tv[KP - 1] = val; ti[KP - 1] = colg0 + cbk * 16 + cloc + e;
            #pragma unroll
            for (int m = KP - 1; m > 0; --m) {
              if (tv[m] > tv[m - 1]) {
                float q = tv[m]; tv[m] = tv[m - 1]; tv[m - 1] = q;
                int   x = ti[m]; ti[m] = ti[m - 1]; ti[m - 1] = x;
              }
            }
          }
        }
      }
    }
    __syncthreads();   // nxt fully staged; cur reads done before it's rewritten
  }

  // ---- merge the 4 col-group lanes of each row (lanes l, l^16, l^32, l^48) ----
  #pragma unroll
  for (int off = 16; off <= 32; off <<= 1) {
    float ov[KP]; int ox[KP];
    #pragma unroll
    for (int j = 0; j < KP; ++j) {
      ov[j] = __shfl_xor(tv[j], off);
      ox[j] = __shfl_xor(ti[j], off);
    }
    #pragma unroll
    for (int j = 0; j < KP; ++j) {
      if (ov[j] > tv[KP - 1] || (ov[j] == tv[KP - 1] && ox[j] < ti[KP - 1])) {
        tv[KP - 1] = ov[j]; ti[KP - 1] = ox[j];
        #pragma unroll
        for (int m = KP - 1; m > 0; --m) {
          if (tv[m] > tv[m - 1] || (tv[m] == tv[m - 1] && ti[m] < ti[m - 1])) {
            float q = tv[m]; tv[m] = tv[m - 1]; tv[m - 1] = q;
            int   x = ti[m]; ti[m] = ti[m - 1]; ti[m - 1] = x;
          }
        }
      }
    }
  }
  if (lane < 16) {
    int* dst = cand + ((size_t)arow * NSPLIT + cs) * KP;
    #pragma unroll
    for (int j = 0; j < KP; ++j) dst[j] = ti[j];
  }
}

// ---- kernel 2: exact fp64 re-rank of 32 candidates/row -> ids + top-8 sims ----
__global__ __launch_bounds__(256) void rerank_kernel(
    const float* __restrict__ Q, const float* __restrict__ C,
    const int* __restrict__ cand, float* __restrict__ out)
{
  const int t = threadIdx.x, w = t >> 6, lane = t & 63;
  const int r = blockIdx.x * 4 + w;
  const f32x4* Q4 = (const f32x4*)(Q + (size_t)r * DIM);

  int cidx = 0;
  if (lane < 32) cidx = cand[(size_t)r * 32 + lane];
  const f32x4* C4 = (const f32x4*)(C + (size_t)cidx * DIM);

  double acc = 0.0;
  #pragma unroll 8
  for (int d4 = 0; d4 < 32; ++d4) {
    f32x4 q = Q4[d4];
    f32x4 c = C4[d4];
    acc += (double)q[0] * (double)c[0];
    acc += (double)q[1] * (double)c[1];
    acc += (double)q[2] * (double)c[2];
    acc += (double)q[3] * (double)c[3];
  }

  double mv = (lane < 32) ? acc : -1.0e300;
  int    mi = (lane < 32) ? cidx : 0x7fffffff;

  float* oi = out;                           // ids as float32
  float* os = out + (size_t)NROWS * 8;       // top-8 sims

  for (int k = 0; k < 8; ++k) {
    double bv = mv; int bi = mi;
    #pragma unroll
    for (int off = 32; off >= 1; off >>= 1) {
      double ov = __shfl_xor(bv, off);
      int    o2 = __shfl_xor(bi, off);
      if (ov > bv || (ov == bv && o2 < bi)) { bv = ov; bi = o2; }
    }
    if (lane == 0) {
      os[(size_t)r * 8 + k] = (float)bv;
      oi[(size_t)r * 8 + k] = (bv >= 0.0) ? (float)bi : -1.0f;
    }
    if (mi == bi) mv = -1.0e300;   // candidate ids unique per row
  }
}

extern "C" void kernel_launch(void* const* d_in, const int* in_sizes, int n_in,
                              void* d_out, int out_size, void* d_ws, size_t ws_size,
                              hipStream_t stream) {
  const float* Q = (const float*)d_in[0];
  const float* C = (const float*)d_in[1];
  float* out = (float*)d_out;
  float* S   = out + (size_t)2 * NROWS * 8;              // all_similarities

  unsigned short* Chi = (unsigned short*)d_ws;           // 4MB
  unsigned short* Clo = Chi + (size_t)NCOLS * DIM;       // 4MB
  int* cand = (int*)(Clo + (size_t)NCOLS * DIM);         // 2MB: [16384][4][8]

  split_kernel<<<dim3(1024), dim3(256), 0, stream>>>(C, Chi, Clo);
  sim_topk_kernel<<<dim3((NROWS / TM) * NSPLIT), dim3(512), 0, stream>>>(Q, Chi, Clo, S, cand);
  rerank_kernel<<<dim3(NROWS / 4), dim3(256), 0, stream>>>(Q, C, cand, out);
}